// Round 3
// baseline (198.116 us; speedup 1.0000x reference)
//
#include <hip/hip_runtime.h>
#include <cfloat>

#define CDESC 32
#define N0 4096
#define N1 512
#define CHUNK0 1024

// ======================= K1: direct 3-D antialias resize =======================
// jax.image.resize (trilinear, antialias, half-pixel): separable triangle taps,
// per-dim normalization. Computed here as one fused 3-D gather per output point.
// blocks 0..127 : stage-0 (64^3 -> 16^3, R=4, KW=8), 1 thread / point
// blocks 128..255: stage-1 (64^3 -> 8^3,  R=8, KW=16), 8 threads / point (z-split)
// Also inits acc[0..3]=0 and slot[] = ~0 (argmin combine slots).
__global__ __launch_bounds__(256) void resize_all(
        const float* __restrict__ csrc, const float* __restrict__ ctgt,
        float4* __restrict__ ps0, float4* __restrict__ pt0,
        float4* __restrict__ ps1, float4* __restrict__ pt1,
        unsigned long long* __restrict__ slot, float* __restrict__ acc) {
    int gid = blockIdx.x * 256 + threadIdx.x;
    if (gid < 4) acc[gid] = 0.f;
    if (gid < 16384) slot[gid] = ~0ull;

    if (blockIdx.x < 128) {
        // ---- stage 0: R=4 ----
        int side = gid >> 14, r = gid & 16383;
        int b = r >> 12, n = r & 4095;
        int x = n & 15, y = (n >> 4) & 15, z = n >> 8;   // block-uniform side,b,z
        const float* in = side ? ctgt : csrc;
        float wx[8], wy[8], wz[8]; int jx[8], jy[8], jz[8];
        float wxs = 0.f, wys = 0.f, wzs = 0.f;
#pragma unroll
        for (int t = 0; t < 8; ++t) {
            float w = 1.f - fabsf((float)t - 3.5f) * 0.25f;
            int j;
            j = 4 * x - 2 + t; { bool v = (unsigned)j < 64u; wx[t] = v ? w : 0.f; jx[t] = v ? j : 0; wxs += wx[t]; }
            j = 4 * y - 2 + t; { bool v = (unsigned)j < 64u; wy[t] = v ? w : 0.f; jy[t] = v ? j : 0; wys += wy[t]; }
            j = 4 * z - 2 + t; { bool v = (unsigned)j < 64u; wz[t] = v ? w : 0.f; jz[t] = v ? j : 0; wzs += wz[t]; }
        }
        float inv = 1.f / (wxs * wys * wzs);
        const float* base = in + (size_t)b * 786432;     // [b][c][z][y][x], c-stride 262144
        float a0 = 0.f, a1 = 0.f, a2 = 0.f;
#pragma unroll 1
        for (int ty = 0; ty < 8; ++ty) {
            int o[8];
#pragma unroll
            for (int i = 0; i < 8; ++i) o[i] = jy[ty] * 64 + jx[i];
#pragma unroll 1
            for (int tz = 0; tz < 8; ++tz) {
                float wzy = wz[tz] * wy[ty];
                const float* p = base + jz[tz] * 4096;
                float s0 = 0.f, s1 = 0.f, s2 = 0.f;
#pragma unroll
                for (int i = 0; i < 8; ++i) {
                    float w = wx[i];
                    s0 = fmaf(w, p[o[i]],          s0);
                    s1 = fmaf(w, p[262144 + o[i]], s1);
                    s2 = fmaf(w, p[524288 + o[i]], s2);
                }
                a0 = fmaf(wzy, s0, a0); a1 = fmaf(wzy, s1, a1); a2 = fmaf(wzy, s2, a2);
            }
        }
        a0 *= inv; a1 *= inv; a2 *= inv;
        float4* pts = side ? pt0 : ps0;
        pts[b * N0 + n] = make_float4(a0, a1, a2, a0 * a0 + a1 * a1 + a2 * a2);
    } else {
        // ---- stage 1: R=8, 8 sub-threads per point, each takes 2 z-taps ----
        int g = gid - 32768;
        int p = g >> 3, sub = g & 7;
        int side = p >> 11, r = p & 2047;
        int b = r >> 9, n = r & 511;
        int x = n & 7, y = (n >> 3) & 7, z = n >> 6;
        const float* in = side ? ctgt : csrc;
        float wx[16], wy[16]; int jx[16], jy[16];
        float wxs = 0.f, wys = 0.f, wzs = 0.f;
#pragma unroll
        for (int t = 0; t < 16; ++t) {
            float w = 1.f - fabsf((float)t - 7.5f) * 0.125f;
            int j;
            j = 8 * x - 4 + t; { bool v = (unsigned)j < 64u; wx[t] = v ? w : 0.f; jx[t] = v ? j : 0; wxs += wx[t]; }
            j = 8 * y - 4 + t; { bool v = (unsigned)j < 64u; wy[t] = v ? w : 0.f; jy[t] = v ? j : 0; wys += wy[t]; }
            j = 8 * z - 4 + t; { bool v = (unsigned)j < 64u; wzs += v ? w : 0.f; }
        }
        float wzo[2]; int jzo[2];
#pragma unroll
        for (int k = 0; k < 2; ++k) {
            int t = 2 * sub + k;
            float w = 1.f - fabsf((float)t - 7.5f) * 0.125f;
            int j = 8 * z - 4 + t;
            bool v = (unsigned)j < 64u;
            wzo[k] = v ? w : 0.f; jzo[k] = v ? j : 0;
        }
        const float* base = in + (size_t)b * 786432;
        float a0 = 0.f, a1 = 0.f, a2 = 0.f;
#pragma unroll 1
        for (int ty = 0; ty < 16; ++ty) {
            int o[16];
#pragma unroll
            for (int i = 0; i < 16; ++i) o[i] = jy[ty] * 64 + jx[i];
#pragma unroll
            for (int k = 0; k < 2; ++k) {
                float wzy = wzo[k] * wy[ty];
                const float* pr = base + jzo[k] * 4096;
                float s0 = 0.f, s1 = 0.f, s2 = 0.f;
#pragma unroll
                for (int i = 0; i < 16; ++i) {
                    float w = wx[i];
                    s0 = fmaf(w, pr[o[i]],          s0);
                    s1 = fmaf(w, pr[262144 + o[i]], s1);
                    s2 = fmaf(w, pr[524288 + o[i]], s2);
                }
                a0 = fmaf(wzy, s0, a0); a1 = fmaf(wzy, s1, a1); a2 = fmaf(wzy, s2, a2);
            }
        }
        // reduce the 8 z-partials (lanes 8p..8p+7 are consecutive in-wave)
#pragma unroll
        for (int m = 1; m < 8; m <<= 1) {
            a0 += __shfl_xor(a0, m, 64);
            a1 += __shfl_xor(a1, m, 64);
            a2 += __shfl_xor(a2, m, 64);
        }
        if (sub == 0) {
            float inv = 1.f / (wxs * wys * wzs);
            a0 *= inv; a1 *= inv; a2 *= inv;
            float4* pts = side ? pt1 : ps1;
            pts[b * N1 + n] = make_float4(a0, a1, a2, a0 * a0 + a1 * a1 + a2 * a2);
        }
    }
}

__device__ __forceinline__ void wave_reduce_atomic(float v, float* acc) {
#pragma unroll
    for (int off = 32; off > 0; off >>= 1) v += __shfl_down(v, off, 64);
    if ((threadIdx.x & 63) == 0) atomicAdd(acc, v);
}

// sign-transformed float bits: monotone u32 over the float total order
__device__ __forceinline__ unsigned fbits_mono(float d) {
    unsigned b = __float_as_uint(d);
    return (d >= 0.f) ? (b | 0x80000000u) : ~b;
}

// ======================= K2: argmin (chunked) + fused stage-1 =======================
// blocks 0..255: stage-0 chunk scan; combine across chunks via packed-u64 atomicMin
//   key = (mono(d) << 32) | m  -> lexicographic (d, m) min == jnp.argmin first-min.
// blocks 256..263: stage-1 full scan + gather + cosine + reduce into acc[1].
__global__ __launch_bounds__(256) void argmin_plus_stage1(
        const float4* __restrict__ ps0, const float4* __restrict__ pt0,
        unsigned long long* __restrict__ slot,
        const float4* __restrict__ ps1, const float4* __restrict__ pt1,
        const float* __restrict__ sd1, const float* __restrict__ td1,
        float* __restrict__ acc) {
    __shared__ float4 sm[CHUNK0];
    int tid = threadIdx.x;
    if (blockIdx.x < 256) {
        int bx = blockIdx.x;
        int ntile = bx & 15, chunk = (bx >> 4) & 3, b = bx >> 6;
        const float4* tp = pt0 + b * N0 + chunk * CHUNK0;
        for (int i = tid; i < CHUNK0; i += 256) {
            float4 q = tp[i];
            sm[i] = make_float4(-2.f * q.x, -2.f * q.y, -2.f * q.z, q.w);
        }
        __syncthreads();
        int n = ntile * 256 + tid;
        float4 p = ps0[b * N0 + n];
        float best = FLT_MAX; int bi = 0;
#pragma unroll 8
        for (int m = 0; m < CHUNK0; ++m) {
            float4 q = sm[m];                      // broadcast LDS read, conflict-free
            float d = fmaf(p.x, q.x, fmaf(p.y, q.y, fmaf(p.z, q.z, q.w)));
            if (d < best) { best = d; bi = m; }
        }
        unsigned long long key =
            ((unsigned long long)fbits_mono(best) << 32) | (unsigned)(chunk * CHUNK0 + bi);
        atomicMin(&slot[b * N0 + n], key);
    } else {
        int bx = blockIdx.x - 256;
        int b = bx >> 1;
        const float4* tp = pt1 + b * N1;
        for (int i = tid; i < N1; i += 256) {
            float4 q = tp[i];
            sm[i] = make_float4(-2.f * q.x, -2.f * q.y, -2.f * q.z, q.w);
        }
        __syncthreads();
        int n = (bx & 1) * 256 + tid;
        float4 p = ps1[b * N1 + n];
        float best = FLT_MAX; int bi = 0;
#pragma unroll 8
        for (int m = 0; m < N1; ++m) {
            float4 q = sm[m];
            float d = fmaf(p.x, q.x, fmaf(p.y, q.y, fmaf(p.z, q.z, q.w)));
            if (d < best) { best = d; bi = m; }
        }
        const float* s = sd1 + (size_t)b * CDESC * N1 + n;
        const float* t = td1 + (size_t)b * CDESC * N1 + bi;
        float num = 0.f, s2 = 0.f, t2 = 0.f;
#pragma unroll
        for (int c = 0; c < CDESC; ++c) {
            float a = s[c * N1], g = t[c * N1];
            num = fmaf(a, g, num); s2 = fmaf(a, a, s2); t2 = fmaf(g, g, t2);
        }
        float denom = fmaxf(sqrtf(s2), 1e-8f) * fmaxf(sqrtf(t2), 1e-8f);
        wave_reduce_atomic(num / denom, acc + 1);
    }
}

// ======================= K3: stage-0 cosine + finalize =======================
__global__ __launch_bounds__(256) void cos0_final(
        const unsigned long long* __restrict__ slot,
        const float* __restrict__ sd, const float* __restrict__ td,
        float* __restrict__ acc, float* __restrict__ out) {
    int gid = blockIdx.x * 256 + threadIdx.x;      // 0..16383
    int b = gid >> 12, n = gid & (N0 - 1);
    int nearest = (int)((unsigned)slot[gid] & 4095u);
    const float* s = sd + (size_t)b * CDESC * N0 + n;
    const float* t = td + (size_t)b * CDESC * N0 + nearest;
    float num = 0.f, s2 = 0.f, t2 = 0.f;
#pragma unroll
    for (int c = 0; c < CDESC; ++c) {
        float a = s[c * N0], g = t[c * N0];
        num = fmaf(a, g, num); s2 = fmaf(a, a, s2); t2 = fmaf(g, g, t2);
    }
    float denom = fmaxf(sqrtf(s2), 1e-8f) * fmaxf(sqrtf(t2), 1e-8f);
    wave_reduce_atomic(num / denom, acc + 0);

    __syncthreads();                               // all this block's atomics issued
    if (threadIdx.x == 0) {
        __threadfence();
        unsigned old = atomicAdd((unsigned*)(acc + 2), 1u);
        if (old == 63u) {                          // last of 64 blocks
            float a0 = atomicAdd(acc + 0, 0.f);
            float a1 = atomicAdd(acc + 1, 0.f);    // stage-1 sum, done in K2 (stream order)
            out[0] = 1.f - 0.5f * (a0 * (1.f / 16384.f) + a1 * (1.f / 2048.f));
        }
    }
}

extern "C" void kernel_launch(void* const* d_in, const int* in_sizes, int n_in,
                              void* d_out, int out_size, void* d_ws, size_t ws_size,
                              hipStream_t stream) {
    const float* c_src = (const float*)d_in[0];   // [4,3,64,64,64]
    const float* c_tgt = (const float*)d_in[1];
    const float* sd0   = (const float*)d_in[2];   // [4,32,16,16,16]
    const float* td0   = (const float*)d_in[3];
    const float* sd1   = (const float*)d_in[4];   // [4,32,8,8,8]
    const float* td1   = (const float*)d_in[5];
    float* out = (float*)d_out;

    char* ws = (char*)d_ws;
    float* acc = (float*)ws;                       // [0]=sum0 [1]=sum1 [2]=ticket [3]=pad
    unsigned long long* slot = (unsigned long long*)(ws + 256);   // 16384 u64 (128 KB)
    float4* ps0 = (float4*)(ws + 256 + 131072);    // 16384 float4
    float4* pt0 = ps0 + 16384;
    float4* ps1 = pt0 + 16384;                     // 2048 float4
    float4* pt1 = ps1 + 2048;

    resize_all<<<256, 256, 0, stream>>>(c_src, c_tgt, ps0, pt0, ps1, pt1, slot, acc);
    argmin_plus_stage1<<<264, 256, 0, stream>>>(ps0, pt0, slot, ps1, pt1, sd1, td1, acc);
    cos0_final<<<64, 256, 0, stream>>>(slot, sd0, td0, acc, out);
}

// Round 5
// 158.390 us; speedup vs baseline: 1.2508x; 1.2508x over previous
//
#include <hip/hip_runtime.h>
#include <cfloat>

typedef unsigned long long u64;

#define CDESC 32
#define N0 4096
#define N1 512

// sign-transformed float bits: monotone u32 over the float total order
__device__ __forceinline__ unsigned fbits_mono(float d) {
    unsigned b = __float_as_uint(d);
    return (d >= 0.f) ? (b | 0x80000000u) : ~b;
}

__device__ __forceinline__ void wave_reduce_atomic(float v, float* acc) {
#pragma unroll
    for (int off = 32; off > 0; off >>= 1) v += __shfl_down(v, off, 64);
    if ((threadIdx.x & 63) == 0) atomicAdd(acc, v);
}

// ---------------- pass-1 body: x-filter (bit-exact since R1) ----------------
// in : [B*3][64][64][64]   out: [B*3][64][64][S]
template<int S, int R>
__device__ __forceinline__ void pass1_body(const float* __restrict__ in,
                                           float* __restrict__ out, int idx) {
    int xo = idx & (S - 1);
    int r  = idx / S;
    int y  = r & 63; r >>= 6;
    int z  = r & 63; r >>= 6;
    int bc = r;                                    // 0..11
    const float* row = in + (((bc * 64) + z) * 64 + y) * 64;
    constexpr int KW = 2 * R;
    int j0 = R * xo - R / 2;
    float sum = 0.f, wsum = 0.f;
#pragma unroll
    for (int t = 0; t < KW; ++t) {
        int j = j0 + t;
        float w = 1.f - fabsf((float)t - ((float)R - 0.5f)) / (float)R;
        if (j >= 0 && j < 64) { sum = fmaf(w, row[j], sum); wsum += w; }
    }
    out[idx] = sum / wsum;
}

// K1: both stages' x-filter; zero the accumulators/ticket.
__global__ __launch_bounds__(256) void pass1_both(
        const float* __restrict__ csrc, const float* __restrict__ ctgt,
        float* __restrict__ t16a, float* __restrict__ t16b,
        float* __restrict__ t8a,  float* __restrict__ t8b,
        float* __restrict__ acc) {
    const float* in = blockIdx.y ? ctgt : csrc;
    if (blockIdx.x < 3072) {
        float* out = blockIdx.y ? t16b : t16a;
        pass1_body<16, 4>(in, out, blockIdx.x * 256 + threadIdx.x);
    } else {
        float* out = blockIdx.y ? t8b : t8a;
        pass1_body<8, 8>(in, out, (blockIdx.x - 3072) * 256 + threadIdx.x);
    }
    if (blockIdx.x == 0 && blockIdx.y == 0 && threadIdx.x < 4) acc[threadIdx.x] = 0.f;
}

// ---------------- pass-2 body: y/z filter -> point + |p|^2 (bit-exact since R1) ----------------
template<int S, int R>
__device__ __forceinline__ void pass2_body(const float* __restrict__ t,
                                           float4* __restrict__ pts, int idx) {
    int n = idx & (S * S * S - 1);
    int b = idx / (S * S * S);
    int x = n & (S - 1);
    int y = (n / S) & (S - 1);
    int z = n / (S * S);
    constexpr int KW = 2 * R;
    constexpr int CS = 64 * 64 * S;
    int jy0 = R * y - R / 2;
    int jz0 = R * z - R / 2;
    float wys = 0.f, wzs = 0.f;
#pragma unroll
    for (int tt = 0; tt < KW; ++tt) {
        float w = 1.f - fabsf((float)tt - ((float)R - 0.5f)) / (float)R;
        int jy = jy0 + tt; if (jy >= 0 && jy < 64) wys += w;
        int jz = jz0 + tt; if (jz >= 0 && jz < 64) wzs += w;
    }
    float inv = 1.f / (wys * wzs);
    float a0 = 0.f, a1 = 0.f, a2 = 0.f;
#pragma unroll 1
    for (int tz = 0; tz < KW; ++tz) {
        int jz = jz0 + tz;
        if (jz < 0 || jz >= 64) continue;
        float wz_ = 1.f - fabsf((float)tz - ((float)R - 0.5f)) / (float)R;
        const float* bz = t + (size_t)b * 3 * CS + jz * (64 * S) + x;
#pragma unroll
        for (int ty = 0; ty < KW; ++ty) {
            int jy = jy0 + ty;
            if (jy < 0 || jy >= 64) continue;
            float w = wz_ * (1.f - fabsf((float)ty - ((float)R - 0.5f)) / (float)R);
            const float* p = bz + jy * S;
            a0 = fmaf(w, p[0],      a0);
            a1 = fmaf(w, p[CS],     a1);
            a2 = fmaf(w, p[2 * CS], a2);
        }
    }
    a0 *= inv; a1 *= inv; a2 *= inv;
    pts[idx] = make_float4(a0, a1, a2, a0 * a0 + a1 * a1 + a2 * a2);
}

// K2: both stages' y/z-filter.
__global__ __launch_bounds__(256) void pass2_both(
        const float* __restrict__ t16a, const float* __restrict__ t16b,
        const float* __restrict__ t8a,  const float* __restrict__ t8b,
        float4* __restrict__ ps0, float4* __restrict__ pt0,
        float4* __restrict__ ps1, float4* __restrict__ pt1) {
    if (blockIdx.x < 64) {
        const float* t = blockIdx.y ? t16b : t16a;
        float4* pts    = blockIdx.y ? pt0  : ps0;
        pass2_body<16, 4>(t, pts, blockIdx.x * 256 + threadIdx.x);
    } else {
        const float* t = blockIdx.y ? t8b : t8a;
        float4* pts    = blockIdx.y ? pt1  : ps1;
        pass2_body<8, 8>(t, pts, (blockIdx.x - 64) * 256 + threadIdx.x);
    }
}

// ======================= K3: argmin + cosine, everything =======================
// blocks 0..255: stage-0. Block owns 64 points (b = bx>>6, ntile = bx&63);
//   4 threads/point (quarter q = tid>>6), full 4096-m scan via 4 sequential
//   16 KB LDS chunks. Per-thread m ascends (chunk-major), strict < keeps the
//   first min; cross-thread combine by min of packed (mono(d)<<32 | m) keys
//   == lexicographic (d, m) == jnp.argmin first-min. Then gather + cosine.
// blocks 256..263: stage-1 fused scan + cosine (verified R2 body).
// 264-block ticket on acc[2] finalizes out.
__global__ __launch_bounds__(256) void nn_cos_all(
        const float4* __restrict__ ps0, const float4* __restrict__ pt0,
        const float* __restrict__ sd0, const float* __restrict__ td0,
        const float4* __restrict__ ps1, const float4* __restrict__ pt1,
        const float* __restrict__ sd1, const float* __restrict__ td1,
        float* acc, float* __restrict__ out) {
    __shared__ __align__(16) float4 sm[1024];      // 16 KB target tile
    __shared__ u64 keys[256];                      // 2 KB combine keys
    const int tid = threadIdx.x;
    const int bx  = blockIdx.x;

    if (bx < 256) {
        int b = bx >> 6, ntile = bx & 63;
        int p = tid & 63, q = tid >> 6;
        int n = ntile * 64 + p;
        float4 P = ps0[b * N0 + n];
        float best = FLT_MAX; int bi = 0;
        const int mb = q * 256;
#pragma unroll 1
        for (int c = 0; c < 4; ++c) {
            const float4* tp = pt0 + b * N0 + c * 1024;
            __syncthreads();                       // protect sm from prev readers
            for (int i = tid; i < 1024; i += 256) {
                float4 qq = tp[i];
                sm[i] = make_float4(-2.f * qq.x, -2.f * qq.y, -2.f * qq.z, qq.w);
            }
            __syncthreads();
#pragma unroll 8
            for (int k = 0; k < 256; ++k) {
                float4 Q = sm[mb + k];             // broadcast, conflict-free
                float d = fmaf(P.x, Q.x, fmaf(P.y, Q.y, fmaf(P.z, Q.z, Q.w)));
                if (d < best) { best = d; bi = c * 1024 + mb + k; }
            }
        }
        keys[tid] = ((u64)fbits_mono(best) << 32) | (unsigned)bi;
        __syncthreads();
        if (tid < 64) {                            // wave 0: one lane per point
            u64 k0 = keys[tid],       k1 = keys[tid + 64];
            u64 k2 = keys[tid + 128], k3 = keys[tid + 192];
            u64 ka = k0 < k1 ? k0 : k1;
            u64 kb = k2 < k3 ? k2 : k3;
            u64 kk = ka < kb ? ka : kb;
            int nearest = (int)(unsigned)(kk & 0xFFFFFFFFull);
            const float* s = sd0 + (size_t)b * CDESC * N0 + n;   // n: p==tid here
            const float* t = td0 + (size_t)b * CDESC * N0 + nearest;
            float num = 0.f, s2 = 0.f, t2 = 0.f;
#pragma unroll
            for (int c = 0; c < CDESC; ++c) {
                float a = s[c * N0], g = t[c * N0];
                num = fmaf(a, g, num); s2 = fmaf(a, a, s2); t2 = fmaf(g, g, t2);
            }
            float denom = fmaxf(sqrtf(s2), 1e-8f) * fmaxf(sqrtf(t2), 1e-8f);
            wave_reduce_atomic(num / denom, acc + 0);
        }
    } else {
        int bb = bx - 256;
        int b = bb >> 1;
        const float4* tp = pt1 + b * N1;
        for (int i = tid; i < N1; i += 256) {
            float4 qq = tp[i];
            sm[i] = make_float4(-2.f * qq.x, -2.f * qq.y, -2.f * qq.z, qq.w);
        }
        __syncthreads();
        int n = (bb & 1) * 256 + tid;
        float4 P = ps1[b * N1 + n];
        float best = FLT_MAX; int bi = 0;
#pragma unroll 8
        for (int m = 0; m < N1; ++m) {
            float4 Q = sm[m];
            float d = fmaf(P.x, Q.x, fmaf(P.y, Q.y, fmaf(P.z, Q.z, Q.w)));
            if (d < best) { best = d; bi = m; }    // ascending m: first-min
        }
        const float* s = sd1 + (size_t)b * CDESC * N1 + n;
        const float* t = td1 + (size_t)b * CDESC * N1 + bi;
        float num = 0.f, s2 = 0.f, t2 = 0.f;
#pragma unroll
        for (int c = 0; c < CDESC; ++c) {
            float a = s[c * N1], g = t[c * N1];
            num = fmaf(a, g, num); s2 = fmaf(a, a, s2); t2 = fmaf(g, g, t2);
        }
        float denom = fmaxf(sqrtf(s2), 1e-8f) * fmaxf(sqrtf(t2), 1e-8f);
        wave_reduce_atomic(num / denom, acc + 1);
    }

    __syncthreads();                               // block's atomics all issued
    if (tid == 0) {
        __threadfence();                           // make them device-visible
        unsigned old = atomicAdd((unsigned*)(acc + 2), 1u);
        if (old == 263u) {                         // last of 264 blocks
            float a0 = atomicAdd(acc + 0, 0.f);    // coherent reads
            float a1 = atomicAdd(acc + 1, 0.f);
            out[0] = 1.f - 0.5f * (a0 * (1.f / 16384.f) + a1 * (1.f / 2048.f));
        }
    }
}

extern "C" void kernel_launch(void* const* d_in, const int* in_sizes, int n_in,
                              void* d_out, int out_size, void* d_ws, size_t ws_size,
                              hipStream_t stream) {
    const float* c_src = (const float*)d_in[0];   // [4,3,64,64,64]
    const float* c_tgt = (const float*)d_in[1];
    const float* sd0   = (const float*)d_in[2];   // [4,32,16,16,16]
    const float* td0   = (const float*)d_in[3];
    const float* sd1   = (const float*)d_in[4];   // [4,32,8,8,8]
    const float* td1   = (const float*)d_in[5];
    float* out = (float*)d_out;

    char* ws = (char*)d_ws;
    float* acc  = (float*)ws;                      // [0]=sum0 [1]=sum1 [2]=ticket [3]=pad
    float* t16a = (float*)(ws + 256);              // 786432 floats each
    float* t16b = t16a + 786432;
    float* t8a  = t16b + 786432;                   // 393216 floats each
    float* t8b  = t8a + 393216;
    float4* ps0 = (float4*)(t8b + 393216);         // 16384 float4 (16B-aligned)
    float4* pt0 = ps0 + 16384;
    float4* ps1 = pt0 + 16384;                     // 2048 float4
    float4* pt1 = ps1 + 2048;

    pass1_both<<<dim3(4608, 2), 256, 0, stream>>>(c_src, c_tgt, t16a, t16b, t8a, t8b, acc);
    pass2_both<<<dim3(72, 2),   256, 0, stream>>>(t16a, t16b, t8a, t8b, ps0, pt0, ps1, pt1);
    nn_cos_all<<<264, 256, 0, stream>>>(ps0, pt0, sd0, td0, ps1, pt1, sd1, td1, acc, out);
}